// Round 1
// 795.721 us; speedup vs baseline: 1.0074x; 1.0074x over previous
//
#include <hip/hip_runtime.h>
#include <math.h>

// Problem constants
#define NN      65536
#define GG      64
#define NPG     1024
#define KEIG    32
#define NBUN    64
#define BDIM    4
#define CH      256        // IN_CH == GNN_DIM == NB*BD
#define NBP     384
#define NEDGE   524288

using f16x8 = __attribute__((ext_vector_type(8))) _Float16;
using f16x4 = __attribute__((ext_vector_type(4))) _Float16;
using f32x4 = __attribute__((ext_vector_type(4))) float;

__device__ __forceinline__ float gelu_f(float x) {
    return 0.5f * x * (1.0f + erff(x * 0.70710678118654752440f));
}

#define GLL(g, l) __builtin_amdgcn_global_load_lds( \
    (const __attribute__((address_space(1))) void*)(g), \
    (__attribute__((address_space(3))) void*)(l), 16, 0, 0)

// ---------------------------------------------------------------------------
// fp16 MFMA GEMM: C = post( A[M,KTOT] @ W ), W transposed as Wt[NOUT,KTOT].
// Block tile 128x128, 4 waves (2x2) of 64x64, BK=32, mfma_f32_16x16x32_f16,
// global_load_lds(16B) with XOR-swizzled 16B chunks (conflict-free b128 reads).
// 3-deep pipelined staging (triple-buffered LDS, counted vmcnt, raw s_barrier):
//   prologue stages t=0,1; iter t stages t+2, waits vmcnt(8) (keeps 8 loads of
//   tiles t+1,t+2 in flight ACROSS the barrier), computes tile t.
//   Trailing barrier per iter protects buf (t%3) from the t+3 overwrite, which
//   any wave can only issue after passing that barrier (race-free by count).
// DUAL: A = concat_k(A1, A2), KTOT=512.
// RESA: + (float)A1[m,n] residual, read-only (requires NOUT==256).
// WF: write fp32 Cf.  W16: write fp16 C16.
// Outputs disjoint from ALL inputs (graph-replay safety).
// ---------------------------------------------------------------------------
template<int NOUT, int KTOT, bool DUAL, bool ACT, bool RESA, bool WF, bool W16>
__global__ __launch_bounds__(256) void mgemm_k(
    const _Float16* __restrict__ A1, const _Float16* __restrict__ A2,
    const _Float16* __restrict__ Wt, const float* __restrict__ bias,
    float* __restrict__ Cf, _Float16* __restrict__ C16)
{
    __shared__ _Float16 Alds[3 * 128 * 32];   // 24 KB, 3 stages x 512 chunks
    __shared__ _Float16 Blds[3 * 128 * 32];

    const int tid  = threadIdx.x;
    const int lane = tid & 63;
    const int wave = tid >> 6;
    const int wm   = wave >> 1;        // wave m-tile (0..1)
    const int wn   = wave & 1;         // wave n-tile (0..1)
    const int m0   = blockIdx.y * 128;
    const int n0   = blockIdx.x * 128;

    // staging chunks: o = tid (rows 0..63) and o+256 (rows 64..127)
    // chunk o holds tile chunk (r = o>>2, c = ((o&3) - (o>>3)) & 3)
    const int o1 = tid,        r1 = o1 >> 2, c1 = ((o1 & 3) - (o1 >> 3)) & 3;
    const int o2 = tid + 256,  r2 = o2 >> 2, c2 = ((o2 & 3) - (o2 >> 3)) & 3;

    // fragment LDS element offsets: chunk(r,c) = r*4 + ((c + (r>>1)) & 3)
    int aoff[4], boff[4];
#pragma unroll
    for (int t = 0; t < 4; t++) {
        int ra = wm * 64 + t * 16 + (lane & 15);
        int rb = wn * 64 + t * 16 + (lane & 15);
        int cc = lane >> 4;
        aoff[t] = (ra * 4 + ((cc + (ra >> 1)) & 3)) * 8;
        boff[t] = (rb * 4 + ((cc + (rb >> 1)) & 3)) * 8;
    }

    f32x4 acc[4][4];
#pragma unroll
    for (int i = 0; i < 4; i++)
#pragma unroll
        for (int j = 0; j < 4; j++) acc[i][j] = 0.f;

    constexpr int NT = KTOT / 32;

    // stage tile t into LDS buffer st (4 GLL = 4 outstanding vmem per wave)
    auto stage = [&](int t, int st) {
        const _Float16* As = A1; int ka = t * 32;
        if (DUAL && ka >= 256) { As = A2; ka -= 256; }
        _Float16* Ab = Alds + st * 4096;
        _Float16* Bb = Blds + st * 4096;
        GLL(As + (size_t)(m0 + r1) * 256 + ka + c1 * 8, Ab + (wave * 64) * 8);
        GLL(As + (size_t)(m0 + r2) * 256 + ka + c2 * 8, Ab + ((256 + wave * 64)) * 8);
        GLL(Wt + (size_t)(n0 + r1) * KTOT + t * 32 + c1 * 8, Bb + (wave * 64) * 8);
        GLL(Wt + (size_t)(n0 + r2) * KTOT + t * 32 + c2 * 8, Bb + ((256 + wave * 64)) * 8);
    };

    stage(0, 0);
    stage(1, 1);
    int ist = 2, cst = 0;
#pragma unroll
    for (int t = 0; t < NT; ++t) {
        if (t + 2 < NT) {
            stage(t + 2, ist);
            ist = (ist == 2) ? 0 : ist + 1;
            // oldest 4 (tile t) done; tiles t+1,t+2 (8 loads) stay in flight
            asm volatile("s_waitcnt vmcnt(8)" ::: "memory");
        } else if (t + 2 == NT) {
            asm volatile("s_waitcnt vmcnt(4)" ::: "memory");
        } else {
            asm volatile("s_waitcnt vmcnt(0)" ::: "memory");
        }
        __builtin_amdgcn_s_barrier();   // all waves' tile-t loads landed

        const int cb = cst * 4096;
        f16x8 av[4], bv[4];
#pragma unroll
        for (int q = 0; q < 4; q++) av[q] = *(const f16x8*)&Alds[cb + aoff[q]];
#pragma unroll
        for (int q = 0; q < 4; q++) bv[q] = *(const f16x8*)&Blds[cb + boff[q]];
        __builtin_amdgcn_s_setprio(1);
#pragma unroll
        for (int mt = 0; mt < 4; mt++)
#pragma unroll
            for (int nt = 0; nt < 4; nt++)
                acc[mt][nt] = __builtin_amdgcn_mfma_f32_16x16x32_f16(
                    av[mt], bv[nt], acc[mt][nt], 0, 0, 0);
        __builtin_amdgcn_s_setprio(0);
        __builtin_amdgcn_s_barrier();   // reads of buf cst done -> safe to
                                        // overwrite at iter t+1 (tile t+3)
        cst = (cst == 2) ? 0 : cst + 1;
    }

    // epilogue: C[m = quad*4+reg][n = lane&15] per 16x16 tile (m89 layout)
    const int rbase = (lane >> 4) * 4;
    const int ncol  = lane & 15;
#pragma unroll
    for (int mt = 0; mt < 4; mt++) {
#pragma unroll
        for (int nt = 0; nt < 4; nt++) {
            const int n = n0 + wn * 64 + nt * 16 + ncol;
            const float bs = bias[n];
#pragma unroll
            for (int i = 0; i < 4; i++) {
                const int m = m0 + wm * 64 + mt * 16 + rbase + i;
                const size_t idx = (size_t)m * NOUT + n;
                float v = acc[mt][nt][i] + bs;
                if (ACT) v = gelu_f(v);
                if (RESA) v += (float)A1[(size_t)m * 256 + n];
                if (WF) Cf[idx] = v;
                if (W16) C16[idx] = (_Float16)v;
            }
        }
    }
}

// ---------------------------------------------------------------------------
__global__ void zero_k(float* __restrict__ p, size_t n)
{
    size_t i = (size_t)blockIdx.x * blockDim.x + threadIdx.x;
    float4* p4 = (float4*)p;
    size_t n4 = n >> 2;
    for (size_t j = i; j < n4; j += (size_t)gridDim.x * blockDim.x)
        p4[j] = make_float4(0.f, 0.f, 0.f, 0.f);
}

// fp32 -> fp16 convert (4 elems/thread)
__global__ __launch_bounds__(256) void cvt16_k(
    const float* __restrict__ in, _Float16* __restrict__ out)
{
    size_t i = (size_t)blockIdx.x * 256 + threadIdx.x;
    float4 v = ((const float4*)in)[i];
    f16x4 o = { (_Float16)v.x, (_Float16)v.y, (_Float16)v.z, (_Float16)v.w };
    ((f16x4*)out)[i] = o;
}

// weight transpose+convert: Wt[n*ldw + koff + k] = f16(W[k*N + n]); K=256
__global__ __launch_bounds__(256) void twt16_k(
    const float* __restrict__ W, _Float16* __restrict__ Wt,
    int N, int ldw, int koff)
{
    int i = blockIdx.x * 256 + threadIdx.x;   // over 256*N
    int k = i & 255, n = i >> 8;
    if (n < N) Wt[(size_t)n * ldw + koff + k] = (_Float16)W[(size_t)k * N + n];
}

__global__ void bcomb_k(const float* __restrict__ a, const float* __restrict__ b,
                        float* __restrict__ o)
{
    int i = blockIdx.x * 256 + threadIdx.x;
    if (i < 512) o[i] = a[i] + b[i];
}

// ---------------------------------------------------------------------------
// CSR build: histogram of dst, exclusive scan, cursor fill
// ---------------------------------------------------------------------------
__global__ __launch_bounds__(256) void hist_k(const int* __restrict__ ei, int* __restrict__ deg)
{
    int e = blockIdx.x * 256 + threadIdx.x;
    if (e < NEDGE) atomicAdd(&deg[ei[NEDGE + e]], 1);
}

__global__ __launch_bounds__(1024) void scan_k(
    const int* __restrict__ deg, int* __restrict__ off, int* __restrict__ cursor)
{
    __shared__ int sh[1024];
    const int tid = threadIdx.x;
    const int base = tid * 64;
    int s = 0;
#pragma unroll 8
    for (int i = 0; i < 64; i++) s += deg[base + i];
    const int mysum = s;
    sh[tid] = s;
    __syncthreads();
    for (int ofs = 1; ofs < 1024; ofs <<= 1) {
        int v = (tid >= ofs) ? sh[tid - ofs] : 0;
        __syncthreads();
        sh[tid] += v;
        __syncthreads();
    }
    int running = sh[tid] - mysum;
    for (int i = 0; i < 64; i++) {
        off[base + i] = running;
        cursor[base + i] = running;
        running += deg[base + i];
    }
    if (tid == 1023) off[NN] = running;
}

__global__ __launch_bounds__(256) void fill_k(
    const int* __restrict__ ei, int* __restrict__ cursor, int* __restrict__ csr)
{
    int e = blockIdx.x * 256 + threadIdx.x;
    if (e < NEDGE) {
        int d = ei[NEDGE + e];
        int pos = atomicAdd(&cursor[d], 1);
        csr[pos] = ei[e];   // src
    }
}

// ---------------------------------------------------------------------------
// Gather segment-sum over fp16 h: fp32 accum, fp16 out
// ---------------------------------------------------------------------------
__global__ __launch_bounds__(256) void gather16_k(
    const _Float16* __restrict__ h, const int* __restrict__ off,
    const int* __restrict__ csr, _Float16* __restrict__ agg)
{
    const int lane = threadIdx.x & 63;
    const int n = blockIdx.x * 4 + (threadIdx.x >> 6);
    const int s0 = off[n], s1 = off[n + 1];
    float a0 = 0.f, a1 = 0.f, a2 = 0.f, a3 = 0.f;
    int j = s0;
    for (; j + 1 < s1; j += 2) {
        f16x4 va = ((const f16x4*)(h + (size_t)csr[j] * CH))[lane];
        f16x4 vb = ((const f16x4*)(h + (size_t)csr[j + 1] * CH))[lane];
        a0 += (float)va[0] + (float)vb[0]; a1 += (float)va[1] + (float)vb[1];
        a2 += (float)va[2] + (float)vb[2]; a3 += (float)va[3] + (float)vb[3];
    }
    if (j < s1) {
        f16x4 va = ((const f16x4*)(h + (size_t)csr[j] * CH))[lane];
        a0 += (float)va[0]; a1 += (float)va[1]; a2 += (float)va[2]; a3 += (float)va[3];
    }
    f16x4 o = { (_Float16)a0, (_Float16)a1, (_Float16)a2, (_Float16)a3 };
    ((f16x4*)(agg + (size_t)n * CH))[lane] = o;
}

// ---------------------------------------------------------------------------
// Householder Q from 6 fp16 params (BD=4: 3 reflectors)
// ---------------------------------------------------------------------------
__device__ __forceinline__ void make_Q(const _Float16* __restrict__ p, float Q[4][4])
{
#pragma unroll
    for (int i = 0; i < 4; i++)
#pragma unroll
        for (int j = 0; j < 4; j++) Q[i][j] = (i == j) ? 1.f : 0.f;
    int idx = 0;
#pragma unroll
    for (int j = 0; j < 3; j++) {
        float v[4] = {0.f, 0.f, 0.f, 0.f};
        v[j] = 1.f;
#pragma unroll
        for (int t = 0; t < 4; t++)
            if (t > j) v[t] = (float)p[idx + t - (j + 1)];
        idx += 3 - j;
        float nrm = v[0]*v[0] + v[1]*v[1] + v[2]*v[2] + v[3]*v[3];
        float s = 2.f / nrm;
#pragma unroll
        for (int i = 0; i < 4; i++) {
            float qv = Q[i][0]*v[0] + Q[i][1]*v[1] + Q[i][2]*v[2] + Q[i][3]*v[3];
            float t0 = s * qv;
#pragma unroll
            for (int c = 0; c < 4; c++) Q[i][c] -= t0 * v[c];
        }
    }
}

// Bundle transform: block = 4 nodes x 64 bundles; node_rep is fp16
template<bool TRANS>
__global__ __launch_bounds__(256) void bundle_k(
    const float* __restrict__ vin, const _Float16* __restrict__ nr,
    float* __restrict__ out)
{
    __shared__ _Float16 pb[4 * NBP];
    const int n0 = blockIdx.x * 4;
    for (int i = threadIdx.x; i < 4 * NBP; i += 256)
        pb[i] = nr[(size_t)n0 * NBP + i];
    __syncthreads();
    const int ln = threadIdx.x >> 6;
    const int b  = threadIdx.x & 63;
    const int n  = n0 + ln;
    float Q[4][4];
    make_Q(&pb[ln * NBP + b * 6], Q);
    float4 xv = ((const float4*)(vin + (size_t)n * CH))[b];
    float in0 = xv.x, in1 = xv.y, in2 = xv.z, in3 = xv.w;
    float4 o;
    if constexpr (!TRANS) {
        o.x = Q[0][0]*in0 + Q[0][1]*in1 + Q[0][2]*in2 + Q[0][3]*in3;
        o.y = Q[1][0]*in0 + Q[1][1]*in1 + Q[1][2]*in2 + Q[1][3]*in3;
        o.z = Q[2][0]*in0 + Q[2][1]*in1 + Q[2][2]*in2 + Q[2][3]*in3;
        o.w = Q[3][0]*in0 + Q[3][1]*in1 + Q[3][2]*in2 + Q[3][3]*in3;
    } else {
        o.x = Q[0][0]*in0 + Q[1][0]*in1 + Q[2][0]*in2 + Q[3][0]*in3;
        o.y = Q[0][1]*in0 + Q[1][1]*in1 + Q[2][1]*in2 + Q[3][1]*in3;
        o.z = Q[0][2]*in0 + Q[1][2]*in1 + Q[2][2]*in2 + Q[3][2]*in3;
        o.w = Q[0][3]*in0 + Q[1][3]*in1 + Q[2][3]*in2 + Q[3][3]*in3;
    }
    ((float4*)(out + (size_t)n * CH))[b] = o;
}

// ---------------------------------------------------------------------------
// Spectral kernels
// ---------------------------------------------------------------------------
__global__ __launch_bounds__(256) void spec_proj_k(
    const float* __restrict__ v, const float* __restrict__ eigvec, float* __restrict__ hs)
{
    const int g = blockIdx.x;
    const int nbase = g * NPG + blockIdx.y * 128;
    __shared__ float evs[16][32];
    float acc[32];
#pragma unroll
    for (int k = 0; k < 32; k++) acc[k] = 0.f;
    for (int nt = 0; nt < 128; nt += 16) {
        __syncthreads();
        for (int i = threadIdx.x; i < 512; i += 256) {
            int nn = i >> 5, kk = i & 31;
            evs[nn][kk] = eigvec[(size_t)(nbase + nt + nn) * KEIG + kk];
        }
        __syncthreads();
#pragma unroll 4
        for (int nn = 0; nn < 16; nn++) {
            float hv = v[(size_t)(nbase + nt + nn) * CH + threadIdx.x];
#pragma unroll
            for (int k = 0; k < 32; k++) acc[k] += evs[nn][k] * hv;
        }
    }
    float* o = hs + (size_t)g * KEIG * CH + threadIdx.x;
#pragma unroll
    for (int k = 0; k < 32; k++) atomicAdd(o + k * CH, acc[k]);
}

// out16[g,n,d] = sum_v ev[g,n,v] * hs[g,v,d] * exp(-eigval[g,v]*taus[d>>2])
// (spec_scale fused into the hs load)
__global__ __launch_bounds__(256) void spec_reproj16_k(
    const float* __restrict__ eigvec, const float* __restrict__ hs,
    const float* __restrict__ eigval, const float* __restrict__ taus,
    _Float16* __restrict__ out16)
{
    const int g = blockIdx.x >> 4;
    const int nbase = g * NPG + (blockIdx.x & 15) * 64;
    const float tau = taus[threadIdx.x >> 2];
    float hsr[32];
    const float* hg = hs + (size_t)g * KEIG * CH + threadIdx.x;
#pragma unroll
    for (int k = 0; k < 32; k++)
        hsr[k] = hg[k * CH] * expf(-eigval[g * KEIG + k] * tau);
    __shared__ float evs[64][32];
    for (int i = threadIdx.x; i < 2048; i += 256) {
        int nn = i >> 5, kk = i & 31;
        evs[nn][kk] = eigvec[(size_t)(nbase + nn) * KEIG + kk];
    }
    __syncthreads();
    for (int nn = 0; nn < 64; nn++) {
        float a = 0.f;
#pragma unroll
        for (int k = 0; k < 32; k++) a += evs[nn][k] * hsr[k];
        out16[(size_t)(nbase + nn) * CH + threadIdx.x] = (_Float16)a;
    }
}

// ---------------------------------------------------------------------------
extern "C" void kernel_launch(void* const* d_in, const int* in_sizes, int n_in,
                              void* d_out, int out_size, void* d_ws, size_t ws_size,
                              hipStream_t stream)
{
    const float* x      = (const float*)d_in[0];
    const float* eigvec = (const float*)d_in[1];
    const float* eigval = (const float*)d_in[2];
    const float* taus   = (const float*)d_in[3];
    const float* enc_w  = (const float*)d_in[4];
    const float* enc_b  = (const float*)d_in[5];
    const float* self_w = (const float*)d_in[6];
    const float* self_b = (const float*)d_in[7];
    const float* nb_w   = (const float*)d_in[8];
    const float* nb_b   = (const float*)d_in[9];
    const float* dec_w  = (const float*)d_in[10];
    const float* dec_b  = (const float*)d_in[11];
    const float* lin_w  = (const float*)d_in[12];
    const float* lin_b  = (const float*)d_in[13];
    const int*   ei     = (const int*)d_in[14];
    (void)in_sizes; (void)n_in; (void)out_size; (void)ws_size;

    float* ws = (float*)d_ws;
    // fp16 [NN,256] plane = 16,777,216 halfs = 8,388,608 FLOAT-SLOTS (round-6
    // bug: was sized 4,194,304 -> agg stomped CSR -> wild gathers -> fault).
    // Stream-ordered lifetimes (float-slot offsets):
    //  [0,        8388608)  x16          -> vf1[0:half] / h3
    //  [8388608, 16777216)  h0           -> vf1[half:]  / h3
    //  [16777216,25165824)  h1           -> hs (@16.7M) ; free tail
    //  [25165824,33554432)  agg          -> nr16 part
    //  [33554432,34275329)  CSR ints     -> nr16 part
    //  [25165824,37748736)  nr16 [NN,384] fp16 (dec out; agg+CSR dead)
    //  [37748752,37995024)  weights + lbias
    //  [37995024,46383632)  h2 [NN,256] fp16
    // high-water: 46,383,632 fl = 185.5 MB
    _Float16* x16 = (_Float16*)(ws);
    _Float16* h0  = (_Float16*)(ws + 8388608);
    _Float16* h1  = (_Float16*)(ws + 16777216);
    _Float16* agg = (_Float16*)(ws + 25165824);
    int* ibase  = (int*)(ws + 33554432);
    int* deg    = ibase;                 // NN
    int* off    = ibase + 65536;         // NN+1
    int* cursor = ibase + 131073;        // NN
    int* csr    = ibase + 196609;        // NEDGE (ends slot 34275329)
    _Float16* nr16 = (_Float16*)(ws + 25165824);  // [NN,384] fp16
    float* wb = ws + 37748752;
    _Float16* enc16 = (_Float16*)(wb);            // [256,256]
    _Float16* l1w   = (_Float16*)(wb + 32768);    // [256,512]
    _Float16* l2w   = (_Float16*)(wb + 98304);    // [256,512]
    _Float16* dec16 = (_Float16*)(wb + 163840);   // [384,256]
    _Float16* lin16 = (_Float16*)(wb + 212992);   // [256,256]
    float* lbias = wb + 245760;                   // [2,256] (ends wb+246272)
    _Float16* h2 = (_Float16*)(ws + 37995024);    // [NN,256] fp16
    float* vf1 = ws;                              // [NN,256] fp32 (x16,h0 dead)
    float* hs  = ws + 16777216;                   // [64,32,256] fp32 (h1 dead)
    float* h3  = vf1;                             // vf1 dead after spec_proj

    dim3 blk(256);

    // ---- prep ----
    cvt16_k<<<16384, blk, 0, stream>>>(x, x16);
    twt16_k<<<256, blk, 0, stream>>>(enc_w, enc16, 256, 256, 0);
    twt16_k<<<256, blk, 0, stream>>>(self_w,         l1w, 256, 512, 0);
    twt16_k<<<256, blk, 0, stream>>>(nb_w,           l1w, 256, 512, 256);
    twt16_k<<<256, blk, 0, stream>>>(self_w + 65536, l2w, 256, 512, 0);
    twt16_k<<<256, blk, 0, stream>>>(nb_w + 65536,   l2w, 256, 512, 256);
    twt16_k<<<384, blk, 0, stream>>>(dec_w, dec16, 384, 256, 0);
    twt16_k<<<256, blk, 0, stream>>>(lin_w, lin16, 256, 256, 0);
    bcomb_k<<<2, blk, 0, stream>>>(self_b, nb_b, lbias);
    zero_k<<<64, blk, 0, stream>>>((float*)deg, (size_t)NN);
    hist_k<<<NEDGE / 256, blk, 0, stream>>>(ei, deg);
    scan_k<<<1, 1024, 0, stream>>>(deg, off, cursor);
    fill_k<<<NEDGE / 256, blk, 0, stream>>>(ei, cursor, csr);

    // ---- h0 = gelu(x @ enc_w + enc_b) ----
    mgemm_k<256, 256, false, true, false, false, true><<<dim3(2, 512), blk, 0, stream>>>(
        x16, nullptr, enc16, enc_b, nullptr, h0);

    // ---- GNN layer 1: h1 = gelu([h0,agg]@W + b) + h0 ----
    gather16_k<<<NN / 4, blk, 0, stream>>>(h0, off, csr, agg);
    mgemm_k<256, 512, true, true, true, false, true><<<dim3(2, 512), blk, 0, stream>>>(
        h0, agg, l1w, lbias, nullptr, h1);

    // ---- GNN layer 2: h0 = gelu([h1,agg]@W + b) + h1 ----
    gather16_k<<<NN / 4, blk, 0, stream>>>(h1, off, csr, agg);
    mgemm_k<256, 512, true, true, true, false, true><<<dim3(2, 512), blk, 0, stream>>>(
        h1, agg, l2w, lbias + 256, nullptr, h0);

    // ---- node_rep = h0 @ dec_w + dec_b  (fp16 out; agg+CSR dead) ----
    mgemm_k<384, 256, false, false, false, false, true><<<dim3(3, 512), blk, 0, stream>>>(
        h0, nullptr, dec16, dec_b, nullptr, nr16);

    // ---- vf1 = Q . x  (x16,h0 dead) ----
    bundle_k<false><<<NN / 4, blk, 0, stream>>>(x, nr16, vf1);

    // ---- spectral filter (scale fused into reproj) ----
    zero_k<<<512, blk, 0, stream>>>(hs, (size_t)GG * KEIG * CH);
    spec_proj_k<<<dim3(GG, 8), blk, 0, stream>>>(vf1, eigvec, hs);
    spec_reproj16_k<<<GG * 16, blk, 0, stream>>>(eigvec, hs, eigval, taus, h2);

    // ---- h3 = h2 @ lin_w + lin_b  (fp32 out; vf1 dead) ----
    mgemm_k<256, 256, false, false, false, true, false><<<dim3(2, 512), blk, 0, stream>>>(
        h2, nullptr, lin16, lin_b, h3, nullptr);

    // ---- out = Q^T . h3 ----
    bundle_k<true><<<NN / 4, blk, 0, stream>>>(h3, nr16, (float*)d_out);
}